// Round 1
// baseline (234.713 us; speedup 1.0000x reference)
//
#include <hip/hip_runtime.h>

// Problem constants
#define B_ 8
#define V_ 10000
#define E_ 160000
#define DIN 128
#define DOUT 128
#define M_ (B_*V_)          // 80000 rows
#define NINV (1.0f/80000.0f)
#define BN_EPS 1e-5f

#define GEMM_BLOCKS 625     // 128 rows per block

// Workspace layout (4-byte units):
#define WS_COUNTS  0            // V_            (zeroed)
#define WS_SCL     10000        // 128  (final per-channel scale)
#define WS_SHF     10128        // 128  (final per-channel shift)
#define WS_ROWPTR  10512        // V_+1
#define WS_CURSOR  20513        // V_
#define WS_SSRC    30513        // E_      -> ends 190513
#define WS_EAS     190520       // E_*8    -> ends 1470520 (32B aligned)
#define WS_S       1470520      // M_      -> ends 1550520
#define WS_WPK     1550520      // 16384 = 32768 f16 (16B aligned)
#define WS_XH      1566904      // 5,120,000 units = 10.24M f16
#define WS_AH      6686904      // 5,120,000 units -> ends 11,806,904
#define WS_PART    11806904     // 625*256 = 160,000 -> ends 11,966,904 (47.9MB)
#define WS_ZERO_UNITS 10000     // counts only

typedef __attribute__((ext_vector_type(2))) _Float16 half2_t;
typedef __attribute__((ext_vector_type(4))) _Float16 half4_t;
typedef __attribute__((ext_vector_type(8))) _Float16 half8_t;
typedef __attribute__((ext_vector_type(4))) float f32x4;

__device__ inline half2_t i2h(unsigned i) {
    half2_t h; __builtin_memcpy(&h, &i, 4); return h;
}
__device__ inline unsigned h2i(half2_t h) {
    unsigned i; __builtin_memcpy(&i, &h, 4); return i;
}

// ---------------------------------------------------------------------------
// 1) fused prep: X->f16 row-major (blocks 0..9999)
//              + W fragment-major f16 pack (blocks 10000..10015)
//              + dst histogram (blocks 10016..10640)
// ---------------------------------------------------------------------------
__global__ __launch_bounds__(256) void prep_kernel(
    const float* __restrict__ X, _Float16* __restrict__ Xh,
    const float* __restrict__ Wself, const float* __restrict__ Wnode,
    _Float16* __restrict__ Wpk,
    const int* __restrict__ EI, int* __restrict__ counts)
{
    const int blk = blockIdx.x;
    const int t = threadIdx.x;
    if (blk < 10000) {
        int idx = blk * 256 + t;                 // over M_*DIN/4
        float4 v = ((const float4*)X)[idx];
        half4_t o = { (_Float16)v.x, (_Float16)v.y, (_Float16)v.z, (_Float16)v.w };
        ((half4_t*)Xh)[idx] = o;
    } else if (blk < 10016) {
        int g = (blk - 10000) * 256 + t;         // 0..4095
        int pair = g >> 6;                       // (ks,nt)
        int lane = g & 63;
        int ks = pair >> 3;
        int nt = pair & 7;
        int o = nt * 16 + (lane & 15);
        int k = ks * 32 + (lane >> 4) * 8;
        const float* wsrc = (k < 128) ? (Wself + o * 128 + k)
                                      : (Wnode + o * 128 + (k - 128));
        _Float16* dst = Wpk + ((size_t)pair * 64 + lane) * 8;
#pragma unroll
        for (int j = 0; j < 8; ++j) dst[j] = (_Float16)wsrc[j];
    } else {
        int e = (blk - 10016) * 256 + t;
        if (e < E_) atomicAdd(&counts[EI[2 * e + 1]], 1);
    }
}

// ---------------------------------------------------------------------------
// 2) exclusive prefix sum over counts -> row_ptr, cursor (single block)
// ---------------------------------------------------------------------------
__global__ __launch_bounds__(256) void scan_kernel(
    const int* __restrict__ counts, int* __restrict__ row_ptr,
    int* __restrict__ cursor)
{
    __shared__ int psum[256];
    const int t = threadIdx.x;
    const int base = t * 40;              // 256*40 = 10240 >= V_
    int local[40];
    int s = 0;
#pragma unroll
    for (int i = 0; i < 40; ++i) {
        int idx = base + i;
        int c = (idx < V_) ? counts[idx] : 0;
        local[i] = s;
        s += c;
    }
    psum[t] = s;
    __syncthreads();
    for (int off = 1; off < 256; off <<= 1) {
        int v = (t >= off) ? psum[t - off] : 0;
        __syncthreads();
        psum[t] += v;
        __syncthreads();
    }
    int excl = (t == 0) ? 0 : psum[t - 1];
#pragma unroll
    for (int i = 0; i < 40; ++i) {
        int idx = base + i;
        if (idx < V_) {
            int rp = excl + local[i];
            row_ptr[idx] = rp;
            cursor[idx] = rp;
        }
    }
    if (t == 255) row_ptr[V_] = psum[255];
}

// ---------------------------------------------------------------------------
// 3) scatter edges into dst-sorted buckets; also pre-sort edge_attr for all
//    8 batches into bucket order: EAs[p][b]
// ---------------------------------------------------------------------------
__global__ __launch_bounds__(256) void bucket_kernel(
    const int* __restrict__ EI, const float* __restrict__ EA,
    int* __restrict__ cursor, int* __restrict__ ssrc,
    float* __restrict__ EAs)
{
    int e = blockIdx.x * 256 + threadIdx.x;
    if (e < E_) {
        int src = EI[2 * e];
        int dst = EI[2 * e + 1];
        int p = atomicAdd(&cursor[dst], 1);
        ssrc[p] = src;
        float4 v0, v1;
        v0.x = EA[0 * E_ + e]; v0.y = EA[1 * E_ + e];
        v0.z = EA[2 * E_ + e]; v0.w = EA[3 * E_ + e];
        v1.x = EA[4 * E_ + e]; v1.y = EA[5 * E_ + e];
        v1.z = EA[6 * E_ + e]; v1.w = EA[7 * E_ + e];
        *(float4*)(EAs + (size_t)p * 8) = v0;
        *(float4*)(EAs + (size_t)p * 8 + 4) = v1;
    }
}

// ---------------------------------------------------------------------------
// 4) gather-reduce, f16, 4 edges per load-step, batch-per-XCD swizzled.
// ---------------------------------------------------------------------------
__global__ __launch_bounds__(256) void gather_kernel(
    const _Float16* __restrict__ Xh, const float* __restrict__ EAs,
    const int* __restrict__ row_ptr, const int* __restrict__ ssrc,
    _Float16* __restrict__ Ah, float* __restrict__ S)
{
    const int b = blockIdx.x & 7;             // batch -> XCD
    const int dblk = blockIdx.x >> 3;         // 0..2499
    const int w = threadIdx.x >> 6;           // 4 waves/block
    const int lane = threadIdx.x & 63;
    const int q = lane >> 4;                  // which edge of the 4-pack
    const int sl = lane & 15;                 // 16B segment: halves sl*8..sl*8+7
    const int d = dblk * 4 + w;
    const int wid = b * V_ + d;
    const int k0 = row_ptr[d];
    const int k1 = row_ptr[d + 1];
    const _Float16* Xb = Xh + (size_t)b * V_ * DIN + sl * 8;
    half2_t a0 = (half2_t)0, a1 = (half2_t)0, a2 = (half2_t)0, a3 = (half2_t)0;
    float ea = 0.0f;
    for (int kb = k0; kb < k1; kb += 64) {
        int cnt = min(64, k1 - kb);
        int msrc = 0;
        if (lane < cnt) {
            msrc = ssrc[kb + lane];
            ea += EAs[(size_t)(kb + lane) * 8 + b];
        }
        int j = 0;
        for (; j + 16 <= cnt; j += 16) {
#pragma unroll
            for (int u = 0; u < 4; ++u) {
                int s = __shfl(msrc, j + u * 4 + q);
                uint4 v = *(const uint4*)(Xb + (size_t)s * DIN);
                a0 += i2h(v.x); a1 += i2h(v.y); a2 += i2h(v.z); a3 += i2h(v.w);
            }
        }
        for (; j + 4 <= cnt; j += 4) {
            int s = __shfl(msrc, j + q);
            uint4 v = *(const uint4*)(Xb + (size_t)s * DIN);
            a0 += i2h(v.x); a1 += i2h(v.y); a2 += i2h(v.z); a3 += i2h(v.w);
        }
        if (j < cnt) {
            int s = __shfl(msrc, j + q);
            if (j + q < cnt) {
                uint4 v = *(const uint4*)(Xb + (size_t)s * DIN);
                a0 += i2h(v.x); a1 += i2h(v.y); a2 += i2h(v.z); a3 += i2h(v.w);
            }
        }
    }
    // combine the 4 edge-offset quarters (lanes differing by 32, then 16)
#pragma unroll
    for (int off = 32; off >= 16; off >>= 1) {
        a0 += i2h(__shfl_down(h2i(a0), off));
        a1 += i2h(__shfl_down(h2i(a1), off));
        a2 += i2h(__shfl_down(h2i(a2), off));
        a3 += i2h(__shfl_down(h2i(a3), off));
    }
    // edge_attr wave reduction
    for (int off = 32; off; off >>= 1) ea += __shfl_down(ea, off);
    if (lane == 0) S[wid] = ea;
    if (lane < 16) {
        uint4 o;
        o.x = h2i(a0); o.y = h2i(a1); o.z = h2i(a2); o.w = h2i(a3);
        *(uint4*)(Ah + (size_t)wid * DIN + sl * 8) = o;
    }
}

// ---------------------------------------------------------------------------
// GEMM body shared by stats pass and norm pass (device inline): computes
// acc[2][8] with bias + S*w_edge applied; if STATS, also accumulates the
// block's 256 per-channel sum/sumsq partials into cs/css (LDS).
// ---------------------------------------------------------------------------
template<bool STATS>
__device__ __forceinline__ void gemm_body(
    const _Float16* __restrict__ Xh, const _Float16* __restrict__ Ah,
    const _Float16* __restrict__ Wpk, const float* __restrict__ S,
    const float* __restrict__ bself, const float* __restrict__ wedge,
    int bid, int t, f32x4 (&acc)[2][8], float* cs, float* css)
{
    const int wave = t >> 6;
    const int lane = t & 63;
    const int quad = lane >> 4;
    const int ln = lane & 15;
    const int rowbase = bid * 128 + wave * 32;
    const int m0 = rowbase + ln;
    const int m1 = rowbase + 16 + ln;

    if constexpr (STATS) {
        if (t < 128) { cs[t] = 0.0f; css[t] = 0.0f; }
    }

#pragma unroll
    for (int mt = 0; mt < 2; ++mt)
#pragma unroll
        for (int nt = 0; nt < 8; ++nt) acc[mt][nt] = (f32x4){0.f, 0.f, 0.f, 0.f};

    const _Float16* X0 = Xh + (size_t)m0 * DIN + quad * 8;
    const _Float16* X1 = Xh + (size_t)m1 * DIN + quad * 8;
    const _Float16* A0 = Ah + (size_t)m0 * DIN + quad * 8;
    const _Float16* A1 = Ah + (size_t)m1 * DIN + quad * 8;
    const _Float16* Wl = Wpk + lane * 8;

#pragma unroll
    for (int ks = 0; ks < 8; ++ks) {
        half8_t af0, af1;
        if (ks < 4) {
            af0 = *(const half8_t*)(X0 + ks * 32);
            af1 = *(const half8_t*)(X1 + ks * 32);
        } else {
            af0 = *(const half8_t*)(A0 + (ks - 4) * 32);
            af1 = *(const half8_t*)(A1 + (ks - 4) * 32);
        }
#pragma unroll
        for (int nt = 0; nt < 8; ++nt) {
            half8_t bfr = *(const half8_t*)(Wl + (size_t)(ks * 8 + nt) * 512);
            acc[0][nt] = __builtin_amdgcn_mfma_f32_16x16x32_f16(af0, bfr, acc[0][nt], 0, 0, 0);
            acc[1][nt] = __builtin_amdgcn_mfma_f32_16x16x32_f16(af1, bfr, acc[1][nt], 0, 0, 0);
        }
    }

    float bs[8], we[8];
#pragma unroll
    for (int nt = 0; nt < 8; ++nt) {
        int c = nt * 16 + ln;
        bs[nt] = bself[c];
        we[nt] = wedge[c];
    }
    float psum[8], psq[8];
    if constexpr (STATS) {
#pragma unroll
        for (int nt = 0; nt < 8; ++nt) { psum[nt] = 0.0f; psq[nt] = 0.0f; }
    }

#pragma unroll
    for (int mt = 0; mt < 2; ++mt) {
        const int rbase = rowbase + mt * 16 + quad * 4;
        float sv[4];
#pragma unroll
        for (int r = 0; r < 4; ++r) sv[r] = S[rbase + r];
#pragma unroll
        for (int nt = 0; nt < 8; ++nt) {
#pragma unroll
            for (int r = 0; r < 4; ++r) {
                float h = acc[mt][nt][r] + bs[nt] + sv[r] * we[nt];
                acc[mt][nt][r] = h;
                if constexpr (STATS) {
                    psum[nt] += h;
                    psq[nt] += h * h;
                }
            }
        }
    }
    if constexpr (STATS) {
#pragma unroll
        for (int nt = 0; nt < 8; ++nt) {
            psum[nt] += __shfl_down(psum[nt], 32);
            psum[nt] += __shfl_down(psum[nt], 16);
            psq[nt] += __shfl_down(psq[nt], 32);
            psq[nt] += __shfl_down(psq[nt], 16);
        }
        __syncthreads();
        if (lane < 16) {
#pragma unroll
            for (int nt = 0; nt < 8; ++nt) {
                atomicAdd(&cs[nt * 16 + ln], psum[nt]);
                atomicAdd(&css[nt * 16 + ln], psq[nt]);
            }
        }
        __syncthreads();
    }
}

// ---------------------------------------------------------------------------
// 5) pass A: GEMM for stats only -> 256 partials per block (no H write).
//    Recomputing the GEMM in pass C costs ~5 GFLOP (trivial) and avoids both
//    the 82 MB fp32 H round-trip and any grid-wide barrier.
// ---------------------------------------------------------------------------
__global__ __launch_bounds__(256) void stats_gemm_kernel(
    const _Float16* __restrict__ Xh, const _Float16* __restrict__ Ah,
    const _Float16* __restrict__ Wpk, const float* __restrict__ S,
    const float* __restrict__ bself, const float* __restrict__ wedge,
    float* __restrict__ Partials)
{
    __shared__ float cs[128];
    __shared__ float css[128];
    const int t = threadIdx.x;
    f32x4 acc[2][8];
    gemm_body<true>(Xh, Ah, Wpk, S, bself, wedge, blockIdx.x, t, acc, cs, css);
    Partials[(size_t)blockIdx.x * 256 + t] = (t < 128) ? cs[t] : css[t - 128];
}

// ---------------------------------------------------------------------------
// 6) pass B: reduce partials -> fold mean/rstd/gamma/beta into scl/shf
//    (128 blocks, one channel each; 64 threads stride over 625 partials)
// ---------------------------------------------------------------------------
__global__ __launch_bounds__(64) void finalize_stats_kernel(
    const float* __restrict__ Partials, const float* __restrict__ gamma,
    const float* __restrict__ beta, float* __restrict__ scl,
    float* __restrict__ shf)
{
    const int c = blockIdx.x;       // 0..127
    const int t = threadIdx.x;      // 0..63
    float s = 0.0f, q = 0.0f;
    for (int p = t; p < GEMM_BLOCKS; p += 64) {
        s += Partials[(size_t)p * 256 + c];
        q += Partials[(size_t)p * 256 + 128 + c];
    }
    for (int off = 32; off; off >>= 1) {
        s += __shfl_down(s, off);
        q += __shfl_down(q, off);
    }
    if (t == 0) {
        float mean = s * NINV;
        float rstd = rsqrtf(q * NINV - mean * mean + BN_EPS);
        float sc = gamma[c] * rstd;
        scl[c] = sc;
        shf[c] = beta[c] - mean * sc;
    }
}

// ---------------------------------------------------------------------------
// 7) pass C: GEMM again -> normalize + ReLU from registers, single H write.
// ---------------------------------------------------------------------------
__global__ __launch_bounds__(256) void norm_gemm_kernel(
    const _Float16* __restrict__ Xh, const _Float16* __restrict__ Ah,
    const _Float16* __restrict__ Wpk, const float* __restrict__ S,
    const float* __restrict__ bself, const float* __restrict__ wedge,
    const float* __restrict__ scl, const float* __restrict__ shf,
    float* __restrict__ H)
{
    const int t = threadIdx.x;
    f32x4 acc[2][8];
    gemm_body<false>(Xh, Ah, Wpk, S, bself, wedge, blockIdx.x, t, acc,
                     nullptr, nullptr);

    const int wave = t >> 6;
    const int lane = t & 63;
    const int quad = lane >> 4;
    const int ln = lane & 15;
    const int rowbase = blockIdx.x * 128 + wave * 32;
    float sc[8], sh[8];
#pragma unroll
    for (int nt = 0; nt < 8; ++nt) {
        int c = nt * 16 + ln;
        sc[nt] = scl[c];
        sh[nt] = shf[c];
    }
#pragma unroll
    for (int mt = 0; mt < 2; ++mt) {
        const int rbase = rowbase + mt * 16 + quad * 4;
#pragma unroll
        for (int r = 0; r < 4; ++r) {
            float* Hr = H + (size_t)(rbase + r) * DOUT + ln;
#pragma unroll
            for (int nt = 0; nt < 8; ++nt)
                Hr[nt * 16] = fmaxf(acc[mt][nt][r] * sc[nt] + sh[nt], 0.0f);
        }
    }
}

// ---------------------------------------------------------------------------
extern "C" void kernel_launch(void* const* d_in, const int* in_sizes, int n_in,
                              void* d_out, int out_size, void* d_ws, size_t ws_size,
                              hipStream_t stream)
{
    const float* X      = (const float*)d_in[0];
    const float* EA     = (const float*)d_in[1];
    const float* Wnode  = (const float*)d_in[2];
    const float* Wedge  = (const float*)d_in[3];
    const float* Wself  = (const float*)d_in[4];
    const float* bself  = (const float*)d_in[5];
    const float* gamma  = (const float*)d_in[6];
    const float* beta   = (const float*)d_in[7];
    const int*   EI     = (const int*)d_in[8];

    int*   wsI    = (int*)d_ws;
    float* wsF    = (float*)d_ws;
    int*   counts = wsI + WS_COUNTS;
    float* scl    = wsF + WS_SCL;
    float* shf    = wsF + WS_SHF;
    int*   rowptr = wsI + WS_ROWPTR;
    int*   cursor = wsI + WS_CURSOR;
    int*   ssrc   = wsI + WS_SSRC;
    float* EAs    = wsF + WS_EAS;
    float* S      = wsF + WS_S;
    _Float16* Wpk = (_Float16*)(wsI + WS_WPK);
    _Float16* Xh  = (_Float16*)(wsI + WS_XH);
    _Float16* Ah  = (_Float16*)(wsI + WS_AH);
    float* Partials = wsF + WS_PART;
    float* H      = (float*)d_out;

    hipMemsetAsync(d_ws, 0, (size_t)WS_ZERO_UNITS * 4, stream);

    // fused prep: xcvt (10000 blocks) + W pack (16) + hist (625)
    prep_kernel<<<10641, 256, 0, stream>>>(X, Xh, Wself, Wnode, Wpk, EI, counts);
    scan_kernel<<<1, 256, 0, stream>>>(counts, rowptr, cursor);
    bucket_kernel<<<(E_ + 255) / 256, 256, 0, stream>>>(EI, EA, cursor, ssrc, EAs);

    // gather-reduce -> Ah, S  (batch-per-XCD swizzle, 4 edges/load-step)
    gather_kernel<<<M_ / 4, 256, 0, stream>>>(Xh, EAs, rowptr, ssrc, Ah, S);

    // stats pass (no H), tiny reduce, then norm pass with single H write.
    // Kernel boundaries provide the global sync; no cooperative launch.
    stats_gemm_kernel<<<GEMM_BLOCKS, 256, 0, stream>>>(Xh, Ah, Wpk, S, bself,
                                                       Wedge, Partials);
    finalize_stats_kernel<<<128, 64, 0, stream>>>(Partials, gamma, beta, scl, shf);
    norm_gemm_kernel<<<GEMM_BLOCKS, 256, 0, stream>>>(Xh, Ah, Wpk, S, bself,
                                                      Wedge, scl, shf, H);
}

// Round 2
// 218.733 us; speedup vs baseline: 1.0731x; 1.0731x over previous
//
#include <hip/hip_runtime.h>

// Problem constants
#define B_ 8
#define V_ 10000
#define E_ 160000
#define DIN 128
#define DOUT 128
#define M_ (B_*V_)          // 80000 rows
#define NINV (1.0f/80000.0f)
#define BN_EPS 1e-5f

#define GEMM_BLOCKS 625     // 128 rows per block

// Workspace layout (4-byte units):
#define WS_COUNTS  0            // V_            (zeroed)
#define WS_SCL     10000        // 128  (final per-channel scale)
#define WS_SHF     10128        // 128  (final per-channel shift)
#define WS_ROWPTR  10512        // V_+1
#define WS_CURSOR  20513        // V_
#define WS_SSRC    30513        // E_      -> ends 190513
#define WS_EAS     190520       // E_*8    -> ends 1470520 (32B aligned)
#define WS_S       1470520      // M_      -> ends 1550520
#define WS_WPK     1550520      // 16384 = 32768 f16 (16B aligned)
#define WS_XH      1566904      // 5,120,000 units = 10.24M f16
#define WS_AH      6686904      // 5,120,000 units -> ends 11,806,904
#define WS_PART    11806904     // 625*256 = 160,000 -> ends 11,966,904 (47.9MB)
#define WS_ZERO_UNITS 10000     // counts only

typedef __attribute__((ext_vector_type(2))) _Float16 half2_t;
typedef __attribute__((ext_vector_type(4))) _Float16 half4_t;
typedef __attribute__((ext_vector_type(8))) _Float16 half8_t;
typedef __attribute__((ext_vector_type(4))) float f32x4;

__device__ inline half2_t i2h(unsigned i) {
    half2_t h; __builtin_memcpy(&h, &i, 4); return h;
}
__device__ inline unsigned h2i(half2_t h) {
    unsigned i; __builtin_memcpy(&i, &h, 4); return i;
}

// ---------------------------------------------------------------------------
// 1) fused prep: X->f16 row-major (blocks 0..9999)
//              + W fragment-major f16 pack (blocks 10000..10015)
//              + dst histogram (blocks 10016..10640)
// ---------------------------------------------------------------------------
__global__ __launch_bounds__(256) void prep_kernel(
    const float* __restrict__ X, _Float16* __restrict__ Xh,
    const float* __restrict__ Wself, const float* __restrict__ Wnode,
    _Float16* __restrict__ Wpk,
    const int* __restrict__ EI, int* __restrict__ counts)
{
    const int blk = blockIdx.x;
    const int t = threadIdx.x;
    if (blk < 10000) {
        int idx = blk * 256 + t;                 // over M_*DIN/4
        float4 v = ((const float4*)X)[idx];
        half4_t o = { (_Float16)v.x, (_Float16)v.y, (_Float16)v.z, (_Float16)v.w };
        ((half4_t*)Xh)[idx] = o;
    } else if (blk < 10016) {
        int g = (blk - 10000) * 256 + t;         // 0..4095
        int pair = g >> 6;                       // (ks,nt)
        int lane = g & 63;
        int ks = pair >> 3;
        int nt = pair & 7;
        int o = nt * 16 + (lane & 15);
        int k = ks * 32 + (lane >> 4) * 8;
        const float* wsrc = (k < 128) ? (Wself + o * 128 + k)
                                      : (Wnode + o * 128 + (k - 128));
        _Float16* dst = Wpk + ((size_t)pair * 64 + lane) * 8;
#pragma unroll
        for (int j = 0; j < 8; ++j) dst[j] = (_Float16)wsrc[j];
    } else {
        int e = (blk - 10016) * 256 + t;
        if (e < E_) atomicAdd(&counts[EI[2 * e + 1]], 1);
    }
}

// ---------------------------------------------------------------------------
// 2) exclusive prefix sum over counts -> row_ptr, cursor (single block)
// ---------------------------------------------------------------------------
__global__ __launch_bounds__(256) void scan_kernel(
    const int* __restrict__ counts, int* __restrict__ row_ptr,
    int* __restrict__ cursor)
{
    __shared__ int psum[256];
    const int t = threadIdx.x;
    const int base = t * 40;              // 256*40 = 10240 >= V_
    int local[40];
    int s = 0;
#pragma unroll
    for (int i = 0; i < 40; ++i) {
        int idx = base + i;
        int c = (idx < V_) ? counts[idx] : 0;
        local[i] = s;
        s += c;
    }
    psum[t] = s;
    __syncthreads();
    for (int off = 1; off < 256; off <<= 1) {
        int v = (t >= off) ? psum[t - off] : 0;
        __syncthreads();
        psum[t] += v;
        __syncthreads();
    }
    int excl = (t == 0) ? 0 : psum[t - 1];
#pragma unroll
    for (int i = 0; i < 40; ++i) {
        int idx = base + i;
        if (idx < V_) {
            int rp = excl + local[i];
            row_ptr[idx] = rp;
            cursor[idx] = rp;
        }
    }
    if (t == 255) row_ptr[V_] = psum[255];
}

// ---------------------------------------------------------------------------
// 3) scatter edges into dst-sorted buckets; also pre-sort edge_attr for all
//    8 batches into bucket order: EAs[p][b]
// ---------------------------------------------------------------------------
__global__ __launch_bounds__(256) void bucket_kernel(
    const int* __restrict__ EI, const float* __restrict__ EA,
    int* __restrict__ cursor, int* __restrict__ ssrc,
    float* __restrict__ EAs)
{
    int e = blockIdx.x * 256 + threadIdx.x;
    if (e < E_) {
        int src = EI[2 * e];
        int dst = EI[2 * e + 1];
        int p = atomicAdd(&cursor[dst], 1);
        ssrc[p] = src;
        float4 v0, v1;
        v0.x = EA[0 * E_ + e]; v0.y = EA[1 * E_ + e];
        v0.z = EA[2 * E_ + e]; v0.w = EA[3 * E_ + e];
        v1.x = EA[4 * E_ + e]; v1.y = EA[5 * E_ + e];
        v1.z = EA[6 * E_ + e]; v1.w = EA[7 * E_ + e];
        *(float4*)(EAs + (size_t)p * 8) = v0;
        *(float4*)(EAs + (size_t)p * 8 + 4) = v1;
    }
}

// ---------------------------------------------------------------------------
// 4) gather-reduce, f16, 4 edges per load-step, batch-per-XCD swizzled.
// ---------------------------------------------------------------------------
__global__ __launch_bounds__(256) void gather_kernel(
    const _Float16* __restrict__ Xh, const float* __restrict__ EAs,
    const int* __restrict__ row_ptr, const int* __restrict__ ssrc,
    _Float16* __restrict__ Ah, float* __restrict__ S)
{
    const int b = blockIdx.x & 7;             // batch -> XCD
    const int dblk = blockIdx.x >> 3;         // 0..2499
    const int w = threadIdx.x >> 6;           // 4 waves/block
    const int lane = threadIdx.x & 63;
    const int q = lane >> 4;                  // which edge of the 4-pack
    const int sl = lane & 15;                 // 16B segment: halves sl*8..sl*8+7
    const int d = dblk * 4 + w;
    const int wid = b * V_ + d;
    const int k0 = row_ptr[d];
    const int k1 = row_ptr[d + 1];
    const _Float16* Xb = Xh + (size_t)b * V_ * DIN + sl * 8;
    half2_t a0 = (half2_t)0, a1 = (half2_t)0, a2 = (half2_t)0, a3 = (half2_t)0;
    float ea = 0.0f;
    for (int kb = k0; kb < k1; kb += 64) {
        int cnt = min(64, k1 - kb);
        int msrc = 0;
        if (lane < cnt) {
            msrc = ssrc[kb + lane];
            ea += EAs[(size_t)(kb + lane) * 8 + b];
        }
        int j = 0;
        for (; j + 16 <= cnt; j += 16) {
#pragma unroll
            for (int u = 0; u < 4; ++u) {
                int s = __shfl(msrc, j + u * 4 + q);
                uint4 v = *(const uint4*)(Xb + (size_t)s * DIN);
                a0 += i2h(v.x); a1 += i2h(v.y); a2 += i2h(v.z); a3 += i2h(v.w);
            }
        }
        for (; j + 4 <= cnt; j += 4) {
            int s = __shfl(msrc, j + q);
            uint4 v = *(const uint4*)(Xb + (size_t)s * DIN);
            a0 += i2h(v.x); a1 += i2h(v.y); a2 += i2h(v.z); a3 += i2h(v.w);
        }
        if (j < cnt) {
            int s = __shfl(msrc, j + q);
            if (j + q < cnt) {
                uint4 v = *(const uint4*)(Xb + (size_t)s * DIN);
                a0 += i2h(v.x); a1 += i2h(v.y); a2 += i2h(v.z); a3 += i2h(v.w);
            }
        }
    }
    // combine the 4 edge-offset quarters (lanes differing by 32, then 16)
#pragma unroll
    for (int off = 32; off >= 16; off >>= 1) {
        a0 += i2h(__shfl_down(h2i(a0), off));
        a1 += i2h(__shfl_down(h2i(a1), off));
        a2 += i2h(__shfl_down(h2i(a2), off));
        a3 += i2h(__shfl_down(h2i(a3), off));
    }
    // edge_attr wave reduction
    for (int off = 32; off; off >>= 1) ea += __shfl_down(ea, off);
    if (lane == 0) S[wid] = ea;
    if (lane < 16) {
        uint4 o;
        o.x = h2i(a0); o.y = h2i(a1); o.z = h2i(a2); o.w = h2i(a3);
        *(uint4*)(Ah + (size_t)wid * DIN + sl * 8) = o;
    }
}

// ---------------------------------------------------------------------------
// GEMM body shared by stats pass and norm pass.
// Key change vs R1: Wpk (64 KB) is staged ONCE per block into LDS via
// global_load_lds (width 16, linear dest — fragment-major layout already
// matches), instead of every wave re-reading all 64 KB from L2 (was 64 of
// the 80 VMEM instrs/wave, 160 MB L2 traffic/pass, latency-stalled).
// A-fragments are loaded into registers BEFORE the barrier so they overlap
// the LDS DMA. Inner loop: ds_read_b128 (1 KB contiguous per wave = 2
// lanes/bank, conflict-free) + MFMA only.
// ---------------------------------------------------------------------------
template<bool STATS>
__device__ __forceinline__ void gemm_body(
    const _Float16* __restrict__ Xh, const _Float16* __restrict__ Ah,
    const _Float16* __restrict__ Wpk, const float* __restrict__ S,
    const float* __restrict__ bself, const float* __restrict__ wedge,
    int bid, int t, f32x4 (&acc)[2][8], float* cs, float* css,
    _Float16* wlds)
{
    const int wave = t >> 6;
    const int lane = t & 63;
    const int quad = lane >> 4;
    const int ln = lane & 15;
    const int rowbase = bid * 128 + wave * 32;
    const int m0 = rowbase + ln;
    const int m1 = rowbase + 16 + ln;

    // stage Wpk -> LDS: 64 chunks of 1 KB; wave w copies chunks [w*16, w*16+16)
    // LDS dest is wave-uniform base; HW adds lane*16.
#pragma unroll
    for (int i = 0; i < 16; ++i) {
        int chunk = wave * 16 + i;
        __builtin_amdgcn_global_load_lds(
            (const __attribute__((address_space(1))) void*)
                ((const char*)Wpk + (size_t)chunk * 1024 + lane * 16),
            (__attribute__((address_space(3))) void*)
                ((char*)wlds + (size_t)chunk * 1024),
            16, 0, 0);
    }

    if constexpr (STATS) {
        if (t < 128) { cs[t] = 0.0f; css[t] = 0.0f; }
    }

#pragma unroll
    for (int mt = 0; mt < 2; ++mt)
#pragma unroll
        for (int nt = 0; nt < 8; ++nt) acc[mt][nt] = (f32x4){0.f, 0.f, 0.f, 0.f};

    const _Float16* X0 = Xh + (size_t)m0 * DIN + quad * 8;
    const _Float16* X1 = Xh + (size_t)m1 * DIN + quad * 8;
    const _Float16* A0 = Ah + (size_t)m0 * DIN + quad * 8;
    const _Float16* A1 = Ah + (size_t)m1 * DIN + quad * 8;

    // All 16 A-fragment loads issued up front; they fly concurrently with
    // the global_load_lds DMA above. (~128 VGPRs; 2 blocks/CU by 64KB LDS
    // -> 2 waves/SIMD -> 256-VGPR budget, fits.)
    half8_t afr[2][8];
#pragma unroll
    for (int ks = 0; ks < 4; ++ks) {
        afr[0][ks]     = *(const half8_t*)(X0 + ks * 32);
        afr[1][ks]     = *(const half8_t*)(X1 + ks * 32);
        afr[0][4 + ks] = *(const half8_t*)(A0 + ks * 32);
        afr[1][4 + ks] = *(const half8_t*)(A1 + ks * 32);
    }

    __syncthreads();   // drains vmcnt (af loads + LDS DMA) then barrier

#pragma unroll
    for (int ks = 0; ks < 8; ++ks) {
#pragma unroll
        for (int nt = 0; nt < 8; ++nt) {
            half8_t bfr = *(const half8_t*)(wlds + (size_t)(ks * 8 + nt) * 512 + lane * 8);
            acc[0][nt] = __builtin_amdgcn_mfma_f32_16x16x32_f16(afr[0][ks], bfr, acc[0][nt], 0, 0, 0);
            acc[1][nt] = __builtin_amdgcn_mfma_f32_16x16x32_f16(afr[1][ks], bfr, acc[1][nt], 0, 0, 0);
        }
    }

    float bs[8], we[8];
#pragma unroll
    for (int nt = 0; nt < 8; ++nt) {
        int c = nt * 16 + ln;
        bs[nt] = bself[c];
        we[nt] = wedge[c];
    }
    float psum[8], psq[8];
    if constexpr (STATS) {
#pragma unroll
        for (int nt = 0; nt < 8; ++nt) { psum[nt] = 0.0f; psq[nt] = 0.0f; }
    }

#pragma unroll
    for (int mt = 0; mt < 2; ++mt) {
        const int rbase = rowbase + mt * 16 + quad * 4;
        float sv[4];
#pragma unroll
        for (int r = 0; r < 4; ++r) sv[r] = S[rbase + r];
#pragma unroll
        for (int nt = 0; nt < 8; ++nt) {
#pragma unroll
            for (int r = 0; r < 4; ++r) {
                float h = acc[mt][nt][r] + bs[nt] + sv[r] * we[nt];
                acc[mt][nt][r] = h;
                if constexpr (STATS) {
                    psum[nt] += h;
                    psq[nt] += h * h;
                }
            }
        }
    }
    if constexpr (STATS) {
#pragma unroll
        for (int nt = 0; nt < 8; ++nt) {
            psum[nt] += __shfl_down(psum[nt], 32);
            psum[nt] += __shfl_down(psum[nt], 16);
            psq[nt] += __shfl_down(psq[nt], 32);
            psq[nt] += __shfl_down(psq[nt], 16);
        }
        __syncthreads();
        if (lane < 16) {
#pragma unroll
            for (int nt = 0; nt < 8; ++nt) {
                atomicAdd(&cs[nt * 16 + ln], psum[nt]);
                atomicAdd(&css[nt * 16 + ln], psq[nt]);
            }
        }
        __syncthreads();
    }
}

// ---------------------------------------------------------------------------
// 5) pass A: GEMM for stats only -> 256 partials per block (no H write).
// ---------------------------------------------------------------------------
__global__ __launch_bounds__(256) void stats_gemm_kernel(
    const _Float16* __restrict__ Xh, const _Float16* __restrict__ Ah,
    const _Float16* __restrict__ Wpk, const float* __restrict__ S,
    const float* __restrict__ bself, const float* __restrict__ wedge,
    float* __restrict__ Partials)
{
    __shared__ _Float16 wlds[32768];   // 64 KB
    __shared__ float cs[128];
    __shared__ float css[128];
    const int t = threadIdx.x;
    f32x4 acc[2][8];
    gemm_body<true>(Xh, Ah, Wpk, S, bself, wedge, blockIdx.x, t, acc, cs, css,
                    wlds);
    Partials[(size_t)blockIdx.x * 256 + t] = (t < 128) ? cs[t] : css[t - 128];
}

// ---------------------------------------------------------------------------
// 6) pass B: reduce partials -> fold mean/rstd/gamma/beta into scl/shf
// ---------------------------------------------------------------------------
__global__ __launch_bounds__(64) void finalize_stats_kernel(
    const float* __restrict__ Partials, const float* __restrict__ gamma,
    const float* __restrict__ beta, float* __restrict__ scl,
    float* __restrict__ shf)
{
    const int c = blockIdx.x;       // 0..127
    const int t = threadIdx.x;      // 0..63
    float s = 0.0f, q = 0.0f;
    for (int p = t; p < GEMM_BLOCKS; p += 64) {
        s += Partials[(size_t)p * 256 + c];
        q += Partials[(size_t)p * 256 + 128 + c];
    }
    for (int off = 32; off; off >>= 1) {
        s += __shfl_down(s, off);
        q += __shfl_down(q, off);
    }
    if (t == 0) {
        float mean = s * NINV;
        float rstd = rsqrtf(q * NINV - mean * mean + BN_EPS);
        float sc = gamma[c] * rstd;
        scl[c] = sc;
        shf[c] = beta[c] - mean * sc;
    }
}

// ---------------------------------------------------------------------------
// 7) pass C: GEMM again -> normalize + ReLU from registers, single H write.
// ---------------------------------------------------------------------------
__global__ __launch_bounds__(256) void norm_gemm_kernel(
    const _Float16* __restrict__ Xh, const _Float16* __restrict__ Ah,
    const _Float16* __restrict__ Wpk, const float* __restrict__ S,
    const float* __restrict__ bself, const float* __restrict__ wedge,
    const float* __restrict__ scl, const float* __restrict__ shf,
    float* __restrict__ H)
{
    __shared__ _Float16 wlds[32768];   // 64 KB
    const int t = threadIdx.x;
    f32x4 acc[2][8];
    gemm_body<false>(Xh, Ah, Wpk, S, bself, wedge, blockIdx.x, t, acc,
                     nullptr, nullptr, wlds);

    const int wave = t >> 6;
    const int lane = t & 63;
    const int quad = lane >> 4;
    const int ln = lane & 15;
    const int rowbase = blockIdx.x * 128 + wave * 32;
    float sc[8], sh[8];
#pragma unroll
    for (int nt = 0; nt < 8; ++nt) {
        int c = nt * 16 + ln;
        sc[nt] = scl[c];
        sh[nt] = shf[c];
    }
#pragma unroll
    for (int mt = 0; mt < 2; ++mt) {
        const int rbase = rowbase + mt * 16 + quad * 4;
#pragma unroll
        for (int r = 0; r < 4; ++r) {
            float* Hr = H + (size_t)(rbase + r) * DOUT + ln;
#pragma unroll
            for (int nt = 0; nt < 8; ++nt)
                Hr[nt * 16] = fmaxf(acc[mt][nt][r] * sc[nt] + sh[nt], 0.0f);
        }
    }
}

// ---------------------------------------------------------------------------
extern "C" void kernel_launch(void* const* d_in, const int* in_sizes, int n_in,
                              void* d_out, int out_size, void* d_ws, size_t ws_size,
                              hipStream_t stream)
{
    const float* X      = (const float*)d_in[0];
    const float* EA     = (const float*)d_in[1];
    const float* Wnode  = (const float*)d_in[2];
    const float* Wedge  = (const float*)d_in[3];
    const float* Wself  = (const float*)d_in[4];
    const float* bself  = (const float*)d_in[5];
    const float* gamma  = (const float*)d_in[6];
    const float* beta   = (const float*)d_in[7];
    const int*   EI     = (const int*)d_in[8];

    int*   wsI    = (int*)d_ws;
    float* wsF    = (float*)d_ws;
    int*   counts = wsI + WS_COUNTS;
    float* scl    = wsF + WS_SCL;
    float* shf    = wsF + WS_SHF;
    int*   rowptr = wsI + WS_ROWPTR;
    int*   cursor = wsI + WS_CURSOR;
    int*   ssrc   = wsI + WS_SSRC;
    float* EAs    = wsF + WS_EAS;
    float* S      = wsF + WS_S;
    _Float16* Wpk = (_Float16*)(wsI + WS_WPK);
    _Float16* Xh  = (_Float16*)(wsI + WS_XH);
    _Float16* Ah  = (_Float16*)(wsI + WS_AH);
    float* Partials = wsF + WS_PART;
    float* H      = (float*)d_out;

    hipMemsetAsync(d_ws, 0, (size_t)WS_ZERO_UNITS * 4, stream);

    // fused prep: xcvt (10000 blocks) + W pack (16) + hist (625)
    prep_kernel<<<10641, 256, 0, stream>>>(X, Xh, Wself, Wnode, Wpk, EI, counts);
    scan_kernel<<<1, 256, 0, stream>>>(counts, rowptr, cursor);
    bucket_kernel<<<(E_ + 255) / 256, 256, 0, stream>>>(EI, EA, cursor, ssrc, EAs);

    // gather-reduce -> Ah, S  (batch-per-XCD swizzle, 4 edges/load-step)
    gather_kernel<<<M_ / 4, 256, 0, stream>>>(Xh, EAs, rowptr, ssrc, Ah, S);

    // stats pass (no H), tiny reduce, then norm pass with single H write.
    stats_gemm_kernel<<<GEMM_BLOCKS, 256, 0, stream>>>(Xh, Ah, Wpk, S, bself,
                                                       Wedge, Partials);
    finalize_stats_kernel<<<128, 64, 0, stream>>>(Partials, gamma, beta, scl, shf);
    norm_gemm_kernel<<<GEMM_BLOCKS, 256, 0, stream>>>(Xh, Ah, Wpk, S, bself,
                                                      Wedge, scl, shf, H);
}